// Round 9
// baseline (357.044 us; speedup 1.0000x reference)
//
#include <hip/hip_runtime.h>

#define N_NODES 50000
#define N_EDGES 1600000
#define IN_DIM 512
#define OUT_DIM 256

#define BM 64                  // 782 blocks = 3.05/CU (balanced); X read once (BN=256)
#define BN 256
#define BK 32
#define APAD 8                 // pad rows to 40 shorts = 80 B -> 2-way banks (free)
#define LDA (BK + APAD)

// ---- two-level counting sort geometry ----
#define RPB   128              // rows per bucket (rloc = 7 bits)
#define NBKT  391              // ceil(50000 / 128)
#define CHUNK 4096             // edges per scatter1 block
#define CAP   5120             // per-bucket tmp capacity (mean 4096, sigma 64 -> +16 sigma)

typedef unsigned int u32;
typedef unsigned short u16;
typedef short bf16x8 __attribute__((ext_vector_type(8)));
typedef float f32x4 __attribute__((ext_vector_type(4)));

__device__ __forceinline__ float bf_to_f(u16 u) { return __uint_as_float(((u32)u) << 16); }
__device__ __forceinline__ u16 f_to_bf(float f) {
    u32 u = __float_as_uint(f);
    u32 r = (u + 0x7fffu + ((u >> 16) & 1u)) >> 16;   // RNE
    return (u16)r;
}

// ---------------------------------------------------------------------------
// CSR build, two-level (verified; byte-identical to round-7).
// ---------------------------------------------------------------------------
__global__ __launch_bounds__(256) void scatter1(const int* __restrict__ er,
                                                const int* __restrict__ ec,
                                                const float* __restrict__ ev,
                                                int* __restrict__ cursor,
                                                int2* __restrict__ tmp) {
    __shared__ int  hcnt[NBKT];
    __shared__ int  loff[NBKT];
    __shared__ int  gbase[NBKT];
    __shared__ int  sc[512];
    __shared__ int2 estage[CHUNK];   // 32 KB
    __shared__ u16  bslot[CHUNK];    // 8 KB

    const int t = threadIdx.x;
    const int base = blockIdx.x * CHUNK;
    const int nedge = min(CHUNK, N_EDGES - base);

    for (int k = t; k < NBKT; k += 256) hcnt[k] = 0;
    __syncthreads();

    int w0[16], w1[16], rk[16];
    #pragma unroll
    for (int j = 0; j < 16; ++j) {
        const int i = j * 256 + t;            // coalesced per j
        rk[j] = -1;
        if (i < nedge) {
            const int e = base + i;
            const int r = er[e];
            const int bk = r >> 7;
            w0[j] = ec[e] | ((r & 127) << 16) | (bk << 23);
            w1[j] = __float_as_int(ev[e]);
            rk[j] = atomicAdd(&hcnt[bk], 1);
        }
    }
    __syncthreads();

    sc[t]       = (t < NBKT) ? hcnt[t] : 0;
    sc[t + 256] = (t + 256 < NBKT) ? hcnt[t + 256] : 0;
    __syncthreads();
    #pragma unroll
    for (int off = 1; off < 512; off <<= 1) {
        const int a0 = (t >= off) ? sc[t - off] : 0;
        const int a1 = sc[t + 256 - off];
        __syncthreads();
        sc[t] += a0;
        sc[t + 256] += a1;
        __syncthreads();
    }
    if (t < NBKT)       loff[t]       = sc[t] - hcnt[t];
    if (t + 256 < NBKT) loff[t + 256] = sc[t + 256] - hcnt[t + 256];

    if (t < NBKT && hcnt[t] > 0)
        gbase[t] = t * CAP + atomicAdd(&cursor[t], hcnt[t]);
    if (t + 256 < NBKT && hcnt[t + 256] > 0)
        gbase[t + 256] = (t + 256) * CAP + atomicAdd(&cursor[t + 256], hcnt[t + 256]);
    __syncthreads();

    #pragma unroll
    for (int j = 0; j < 16; ++j) {
        if (rk[j] >= 0) {
            const int bk = ((u32)w0[j]) >> 23;
            const int s = loff[bk] + rk[j];
            estage[s] = make_int2(w0[j], w1[j]);
            bslot[s]  = (u16)bk;
        }
    }
    __syncthreads();

    for (int s = t; s < nedge; s += 256) {
        const int bk = bslot[s];
        const int2 e2 = estage[s];
        const int gpos = gbase[bk] + (s - loff[bk]);
        if (gpos < (bk + 1) * CAP)            // overflow guard (never in practice)
            tmp[gpos] = e2;
    }
}

// per bucket: inline 391-scan of bucket counts, then LDS row-hist + scan ->
// row_ptr, scatter into 32KB L2-resident window with LDS cursors.
__global__ __launch_bounds__(256) void scatter2(const int* __restrict__ cursor,
                                                const int2* __restrict__ tmp,
                                                int* __restrict__ row_ptr,
                                                int2* __restrict__ sedge) {
    __shared__ int sc[512];
    __shared__ int orig[512];
    __shared__ int rcnt[RPB];
    __shared__ int rsc[RPB];
    __shared__ int rcur[RPB];
    const int t = threadIdx.x;
    const int b = blockIdx.x;

    const int c0 = (t < NBKT) ? min(cursor[t], CAP) : 0;
    const int c1 = (t + 256 < NBKT) ? min(cursor[t + 256], CAP) : 0;
    sc[t] = c0;       orig[t] = c0;
    sc[t + 256] = c1; orig[t + 256] = c1;
    __syncthreads();
    #pragma unroll
    for (int off = 1; off < 512; off <<= 1) {
        const int a0 = (t >= off) ? sc[t - off] : 0;
        const int a1 = sc[t + 256 - off];
        __syncthreads();
        sc[t] += a0;
        sc[t + 256] += a1;
        __syncthreads();
    }
    const int gb = sc[b] - orig[b];           // exclusive prefix at bucket b
    const int n  = orig[b];                   // this bucket's edge count
    const int2* src = tmp + (size_t)b * CAP;

    if (b == 0 && t == 0) row_ptr[N_NODES] = N_EDGES;

    if (t < RPB) rcnt[t] = 0;
    __syncthreads();
    for (int i = t; i < n; i += 256)
        atomicAdd(&rcnt[(((u32)src[i].x) >> 16) & 127], 1);
    __syncthreads();

    if (t < RPB) rsc[t] = rcnt[t];
    __syncthreads();
    #pragma unroll
    for (int off = 1; off < RPB; off <<= 1) {
        int a = 0;
        if (t < RPB && t >= off) a = rsc[t - off];
        __syncthreads();
        if (t < RPB) rsc[t] += a;
        __syncthreads();
    }
    if (t < RPB) {
        const int excl = rsc[t] - rcnt[t];
        rcur[t] = gb + excl;
        const int row = b * RPB + t;
        if (row < N_NODES) row_ptr[row] = gb + excl;
    }
    __syncthreads();

    for (int i = t; i < n; i += 256) {
        const int2 e2 = src[i];                       // L2-hot (2nd pass)
        const int rloc = (((u32)e2.x) >> 16) & 127;
        const int pos = atomicAdd(&rcur[rloc], 1);    // LDS atomic
        sedge[pos] = make_int2(e2.x & 0xFFFF, e2.y);  // within 32KB window
    }
}

// ---------------------------------------------------------------------------
// W [512,256] fp32 -> WT [256,512] bf16 (transposed); also zeroes cursor[].
// ---------------------------------------------------------------------------
__global__ __launch_bounds__(256) void wcvt_zero(const float* __restrict__ W,
                                                 u16* __restrict__ WT,
                                                 int* __restrict__ cursor) {
    if (blockIdx.x < 2) {
        const int i = blockIdx.x * 256 + threadIdx.x;
        if (i < NBKT) cursor[i] = 0;
    }
    const int n  = threadIdx.x;
    const int k0 = blockIdx.x * 4;
    ushort4 o;
    o.x = f_to_bf(W[(size_t)(k0 + 0) * OUT_DIM + n]);
    o.y = f_to_bf(W[(size_t)(k0 + 1) * OUT_DIM + n]);
    o.z = f_to_bf(W[(size_t)(k0 + 2) * OUT_DIM + n]);
    o.w = f_to_bf(W[(size_t)(k0 + 3) * OUT_DIM + n]);
    *(ushort4*)(WT + (size_t)n * IN_DIM + k0) = o;
}

// ---------------------------------------------------------------------------
// GEMM: Sb[M,256] = bf16( X[M,512] @ W[512,256] ), MFMA 16x16x32.
// 64x256 tile + REGISTER-PREFETCH DOUBLE BUFFER (T14): next K-tile's global
// loads issue right after the first barrier and fly during ds_read+MFMA.
// (Old loop issued loads only after the prior barrier -> every iter paid a
// serialized ~900cy HBM round-trip; suspected cause of the stable 241us
// remainder.)  +24 VGPR for the staged regs.
// ---------------------------------------------------------------------------
__global__ __launch_bounds__(256) void gemm_mfma(const float* __restrict__ X,
                                                 const u16* __restrict__ WT,
                                                 u16* __restrict__ Sb) {
    __shared__ u16 As[BM * LDA];   //  5,120 B
    __shared__ u16 Bs[BN * LDA];   // 20,480 B

    const int tid  = threadIdx.x;
    const int wave = tid >> 6;          // 0..3
    const int lane = tid & 63;
    const int r0   = blockIdx.x * BM;
    const int wn   = wave * 64;         // 0,64,128,192
    const int l15  = lane & 15;
    const int quad = lane >> 4;

    f32x4 acc[4][4];
    #pragma unroll
    for (int i = 0; i < 4; ++i)
        #pragma unroll
        for (int j = 0; j < 4; ++j) acc[i][j] = (f32x4)0.f;

    // A-staging: 64 rows x 32 k / 256 thr -> 4 thr/row, 8 k each
    const int arow = tid >> 2;
    const int akp  = (tid & 3) * 8;
    const int xrow = min(r0 + arow, N_NODES - 1); // clamp; stores masked
    const float* xsrc = X + (size_t)xrow * IN_DIM + akp;
    // B-staging: 256 rows x 32 k / 256 thr -> 2 thr/row, 16 k, 2 row-halves
    const int brow = tid >> 1;
    const int bkp  = (tid & 1) * 16;
    const u16* bsrc  = WT + (size_t)brow * IN_DIM + bkp;
    const u16* bsrc2 = bsrc + (size_t)128 * IN_DIM;

    // prologue: prefetch K-tile 0 into regs
    float4 fA0 = *(const float4*)(xsrc + 0);
    float4 fA1 = *(const float4*)(xsrc + 4);
    uint4  rB0 = *(const uint4*)(bsrc + 0);
    uint4  rB1 = *(const uint4*)(bsrc + 8);
    uint4  rB2 = *(const uint4*)(bsrc2 + 0);
    uint4  rB3 = *(const uint4*)(bsrc2 + 8);

    for (int kc = 0; kc < IN_DIM; kc += BK) {
        {   // stage regs(kc) -> LDS
            ushort4 p0, p1;
            p0.x = f_to_bf(fA0.x); p0.y = f_to_bf(fA0.y); p0.z = f_to_bf(fA0.z); p0.w = f_to_bf(fA0.w);
            p1.x = f_to_bf(fA1.x); p1.y = f_to_bf(fA1.y); p1.z = f_to_bf(fA1.z); p1.w = f_to_bf(fA1.w);
            *(ushort4*)&As[arow * LDA + akp + 0] = p0;
            *(ushort4*)&As[arow * LDA + akp + 4] = p1;
            *(uint4*)&Bs[brow * LDA + bkp + 0] = rB0;
            *(uint4*)&Bs[brow * LDA + bkp + 8] = rB1;
            *(uint4*)&Bs[(brow + 128) * LDA + bkp + 0] = rB2;
            *(uint4*)&Bs[(brow + 128) * LDA + bkp + 8] = rB3;
        }
        __syncthreads();

        // issue prefetch for kc+BK now; lands while we ds_read+MFMA
        if (kc + BK < IN_DIM) {
            fA0 = *(const float4*)(xsrc + kc + BK + 0);
            fA1 = *(const float4*)(xsrc + kc + BK + 4);
            rB0 = *(const uint4*)(bsrc + kc + BK + 0);
            rB1 = *(const uint4*)(bsrc + kc + BK + 8);
            rB2 = *(const uint4*)(bsrc2 + kc + BK + 0);
            rB3 = *(const uint4*)(bsrc2 + kc + BK + 8);
        }

        bf16x8 af[4], bfr[4];
        #pragma unroll
        for (int mt = 0; mt < 4; ++mt)
            af[mt] = *(const bf16x8*)&As[(mt * 16 + l15) * LDA + quad * 8];
        #pragma unroll
        for (int nt = 0; nt < 4; ++nt)
            bfr[nt] = *(const bf16x8*)&Bs[(wn + nt * 16 + l15) * LDA + quad * 8];
        #pragma unroll
        for (int mt = 0; mt < 4; ++mt)
            #pragma unroll
            for (int nt = 0; nt < 4; ++nt)
                acc[mt][nt] = __builtin_amdgcn_mfma_f32_16x16x32_bf16(
                    af[mt], bfr[nt], acc[mt][nt], 0, 0, 0);
        __syncthreads();
    }

    // epilogue: D[row = quad*4 + r][col = l15] per 16x16 tile; Sb row-major
    #pragma unroll
    for (int mt = 0; mt < 4; ++mt) {
        #pragma unroll
        for (int r = 0; r < 4; ++r) {
            const int grow = r0 + mt * 16 + quad * 4 + r;
            if (grow < N_NODES) {
                u16* dst = Sb + (size_t)grow * OUT_DIM + wn + l15;
                #pragma unroll
                for (int nt = 0; nt < 4; ++nt)
                    dst[nt * 16] = f_to_bf(acc[mt][nt][r]);
            }
        }
    }
}

// ---------------------------------------------------------------------------
// out[r] = bias + sum_{e in row r} val[e] * Sb[col[e]]  (round-7 form, 114us)
// SPLIT into two half-row launches (rbase param): total work identical, but
// the rocprof top-5 cutoff drops ~114 -> ~58us so the hidden remainder
// kernels (gemm? scatter1/2?) must surface next round.
// ---------------------------------------------------------------------------
__global__ __launch_bounds__(256) void csr_spmm(const int* __restrict__ row_ptr,
                                                const int2* __restrict__ sedge,
                                                const u16* __restrict__ Sb,
                                                const float* __restrict__ bias,
                                                float* __restrict__ out,
                                                int rbase) {
    const int wave = threadIdx.x >> 6;
    const int lane = threadIdx.x & 63;
    const int r = rbase + blockIdx.x * 4 + wave;
    if (r >= N_NODES) return;

    const int start = row_ptr[r];
    const int end   = row_ptr[r + 1];

    float4 acc = *(const float4*)(bias + lane * 4);
    const u16* sbase = Sb + lane * 4;

    int e = start;
    // main: full 16-edge batches, no clamping, 16 gathers in flight
    for (; e + 16 <= end; e += 16) {
        int2 ed[16];
        #pragma unroll
        for (int j = 0; j < 16; ++j) ed[j] = sedge[e + j];

        ushort4 sv[16];
        #pragma unroll
        for (int j = 0; j < 16; ++j)
            sv[j] = *(const ushort4*)(sbase + (size_t)ed[j].x * OUT_DIM);

        #pragma unroll
        for (int j = 0; j < 16; ++j) {
            const float vj = __int_as_float(ed[j].y);
            acc.x += vj * bf_to_f(sv[j].x);
            acc.y += vj * bf_to_f(sv[j].y);
            acc.z += vj * bf_to_f(sv[j].z);
            acc.w += vj * bf_to_f(sv[j].w);
        }
    }
    // tail: one clamped batch (row nonempty here since e < end)
    if (e < end) {
        int2 ed[16];
        #pragma unroll
        for (int j = 0; j < 16; ++j)
            ed[j] = sedge[min(e + j, end - 1)];
        #pragma unroll
        for (int j = 0; j < 16; ++j)
            if (e + j >= end) ed[j].y = 0;            // 0.0f bits on padding

        ushort4 sv[16];
        #pragma unroll
        for (int j = 0; j < 16; ++j)
            sv[j] = *(const ushort4*)(sbase + (size_t)ed[j].x * OUT_DIM);

        #pragma unroll
        for (int j = 0; j < 16; ++j) {
            const float vj = __int_as_float(ed[j].y);
            acc.x += vj * bf_to_f(sv[j].x);
            acc.y += vj * bf_to_f(sv[j].y);
            acc.z += vj * bf_to_f(sv[j].z);
            acc.w += vj * bf_to_f(sv[j].w);
        }
    }

    *(float4*)(out + (size_t)r * OUT_DIM + lane * 4) = acc;
}

extern "C" void kernel_launch(void* const* d_in, const int* in_sizes, int n_in,
                              void* d_out, int out_size, void* d_ws, size_t ws_size,
                              hipStream_t stream) {
    const float* X    = (const float*)d_in[0];
    const int*   er   = (const int*)d_in[1];
    const int*   ec   = (const int*)d_in[2];
    const float* ev   = (const float*)d_in[3];
    const float* W    = (const float*)d_in[4];
    const float* bias = (const float*)d_in[5];
    float* out        = (float*)d_out;

    // ws layout (~38.9 MB).  tmp/cursor alias the Sb region: they are dead
    // before gemm_mfma writes Sb (stream-ordered).
    char* ws = (char*)d_ws;
    u16*  Sb      = (u16*) (ws);                       // 25,600,000 B
    int2* tmp     = (int2*)(ws);                       // 16,015,360 B (alias)
    int*  cursor  = (int*) (ws + 16100000);            //      1,564 B (alias)
    int2* sedge   = (int2*)(ws + 25600000);            // 12,800,000 B
    u16*  WT      = (u16*) (ws + 38400000);            //    262,144 B
    int*  row_ptr = (int*) (ws + 38662144);            //    200,004 B

    hipLaunchKernelGGL(wcvt_zero, dim3(IN_DIM / 4), dim3(256), 0, stream,
                       W, WT, cursor);
    hipLaunchKernelGGL(scatter1, dim3((N_EDGES + CHUNK - 1) / CHUNK), dim3(256), 0,
                       stream, er, ec, ev, cursor, tmp);
    hipLaunchKernelGGL(scatter2, dim3(NBKT), dim3(256), 0, stream,
                       cursor, tmp, row_ptr, sedge);
    hipLaunchKernelGGL(gemm_mfma, dim3((N_NODES + BM - 1) / BM), dim3(256), 0,
                       stream, X, WT, Sb);
    hipLaunchKernelGGL(csr_spmm, dim3(25000 / 4), dim3(256), 0, stream,
                       row_ptr, sedge, Sb, bias, out, 0);
    hipLaunchKernelGGL(csr_spmm, dim3(25000 / 4), dim3(256), 0, stream,
                       row_ptr, sedge, Sb, bias, out, 25000);
}